// Round 10
// baseline (1163.608 us; speedup 1.0000x reference)
//
#include <hip/hip_runtime.h>
#include <hip/hip_bf16.h>
#include <math.h>

#define B_    2
#define S_    2048
#define DIM_  4096
#define NH_   32
#define NKV_  8
#define HD_   128
#define NREP_ 4
// NOTE: KVB=32 flash_attn restructure failed correctness 3x (absmax ~130-156)
// despite index algebra verifying by hand. Do not retry blind.
// NOTE: T1 XCD swizzle on gemm_bt REGRESSED +47us (r8). Reverted.
// r9: fused KV GEMM (2 blocks/CU vs 1) saved ~115us. total 1069.

typedef __attribute__((ext_vector_type(8))) short bf16x8;   // 8 bf16 in 4 VGPRs
typedef __attribute__((ext_vector_type(4))) float floatx4;  // MFMA C/D frag

__device__ __forceinline__ unsigned short f2bf(float f) {
    unsigned int u = __float_as_uint(f);
    unsigned int r = (u + 0x7FFFu + ((u >> 16) & 1u)) >> 16;  // RNE
    return (unsigned short)r;
}
__device__ __forceinline__ float bf2f(unsigned short u) {
    return __uint_as_float((unsigned int)u << 16);
}
// packed f32x2 -> bf16x2 (RNE), single HW op; no builtin on gfx950
__device__ __forceinline__ unsigned int cvt_pk_bf16(float lo, float hi) {
    unsigned int r;
    asm("v_cvt_pk_bf16_f32 %0, %1, %2" : "=v"(r) : "v"(lo), "v"(hi));
    return r;
}
// max-reduce over each 16-lane row via DPP row_ror 1,2,4,8 (VALU-only,
// no DS pipe). dpp_ctrl args MUST be literal constants (clang sema).
__device__ __forceinline__ float rowmax16(float x) {
    int t;
    t = __builtin_amdgcn_mov_dpp(__float_as_int(x), 0x121, 0xf, 0xf, true);
    x = fmaxf(x, __int_as_float(t));
    t = __builtin_amdgcn_mov_dpp(__float_as_int(x), 0x122, 0xf, 0xf, true);
    x = fmaxf(x, __int_as_float(t));
    t = __builtin_amdgcn_mov_dpp(__float_as_int(x), 0x124, 0xf, 0xf, true);
    x = fmaxf(x, __int_as_float(t));
    t = __builtin_amdgcn_mov_dpp(__float_as_int(x), 0x128, 0xf, 0xf, true);
    x = fmaxf(x, __int_as_float(t));
    return x;
}
// async global->LDS, 16B per lane; LDS dst = readfirstlane(base) + lane*16
__device__ __forceinline__ void gload_lds16(const unsigned short* g, unsigned short* l) {
    __builtin_amdgcn_global_load_lds(
        (const __attribute__((address_space(1))) void*)g,
        (__attribute__((address_space(3))) void*)l, 16, 0, 0);
}

// ---------------------------------------------------------------------------
// fp32 -> bf16 elementwise (same layout), n % 4 == 0
// ---------------------------------------------------------------------------
__global__ __launch_bounds__(256)
void convert_bf16(const float* __restrict__ in, unsigned short* __restrict__ out,
                  long long n) {
    long long i = ((long long)blockIdx.x * 256 + threadIdx.x) * 4;
    if (i >= n) return;
    const float4 v = *(const float4*)(in + i);
    ushort4 o;
    o.x = f2bf(v.x); o.y = f2bf(v.y); o.z = f2bf(v.z); o.w = f2bf(v.w);
    *(ushort4*)(out + i) = o;
}

// ---------------------------------------------------------------------------
// W fp32 [K][N] -> Wt bf16 [N][K]  (tiled 32x32 transpose, 256 threads)
// ---------------------------------------------------------------------------
__global__ __launch_bounds__(256)
void transpose_conv(const float* __restrict__ W, unsigned short* __restrict__ Wt,
                    int K, int N) {
    __shared__ unsigned short t[32][33];
    const int tx = threadIdx.x & 31, ty = threadIdx.x >> 5;  // ty 0..7
    const int n0 = blockIdx.x * 32, k0 = blockIdx.y * 32;
    for (int i = 0; i < 4; ++i)
        t[ty + i * 8][tx] = f2bf(W[(size_t)(k0 + ty + i * 8) * N + n0 + tx]);
    __syncthreads();
    for (int i = 0; i < 4; ++i)
        Wt[(size_t)(n0 + ty + i * 8) * K + k0 + tx] = t[tx][ty + i * 8];
}

// ---------------------------------------------------------------------------
// GEMM (m97 structure): C[M][N] = A[M][K] @ Bt[N][K]^T, bf16 in, fp32 acc.
// 128x128 tile, BK=32, 256 threads (4 waves, 64x64 each, 4x4 frags).
// Staging via global_load_lds width=16 into UNPADDED LDS (HW layout rule).
// ---------------------------------------------------------------------------
template<bool OUT_BF16>
__global__ __launch_bounds__(256)
void gemm_bt(const unsigned short* __restrict__ A,   // [M][K] bf16
             const unsigned short* __restrict__ Bt,  // [N][K] bf16
             void* __restrict__ C, int M, int N, int K) {
    __shared__ unsigned short As[128 * 32];
    __shared__ unsigned short Bs[128 * 32];
    const int tid  = threadIdx.x;
    const int lane = tid & 63;
    const int wave = tid >> 6;
    const int l16  = lane & 15;
    const int quad = lane >> 4;
    const int tileM = blockIdx.x * 128, tileN = blockIdx.y * 128;
    const int waveM = (wave >> 1) * 64, waveN = (wave & 1) * 64;

    floatx4 acc[4][4] = {};

    // staging geometry: idx = p*256+tid; 16B/lane; row = idx/4 (32 elems/row)
    const int r0 = tid >> 2, ko = (tid & 3) * 8;

    for (int k0 = 0; k0 < K; k0 += 32) {
        for (int p = 0; p < 2; ++p) {
            const int idx = p * 256 + tid;
            const int row = r0 + p * 64;
            gload_lds16(A  + (size_t)(tileM + row) * K + k0 + ko, &As[idx * 8]);
            gload_lds16(Bt + (size_t)(tileN + row) * K + k0 + ko, &Bs[idx * 8]);
        }
        __syncthreads();
        bf16x8 af[4], bfr[4];
        for (int i = 0; i < 4; ++i) {
            af[i]  = *(const bf16x8*)&As[(waveM + i * 16 + l16) * 32 + quad * 8];
            bfr[i] = *(const bf16x8*)&Bs[(waveN + i * 16 + l16) * 32 + quad * 8];
        }
        for (int mi = 0; mi < 4; ++mi)
            for (int ni = 0; ni < 4; ++ni)
                acc[mi][ni] = __builtin_amdgcn_mfma_f32_16x16x32_bf16(
                    af[mi], bfr[ni], acc[mi][ni], 0, 0, 0);
        __syncthreads();
    }
    // epilogue: C/D layout col=lane&15, row=quad*4+reg
    for (int mi = 0; mi < 4; ++mi)
        for (int r = 0; r < 4; ++r) {
            const int row = tileM + waveM + mi * 16 + quad * 4 + r;
            for (int ni = 0; ni < 4; ++ni) {
                const int col = tileN + waveN + ni * 16 + l16;
                if (OUT_BF16)
                    ((unsigned short*)C)[(size_t)row * N + col] = f2bf(acc[mi][ni][r]);
                else
                    ((float*)C)[(size_t)row * N + col] = acc[mi][ni][r];
            }
        }
}

// ---------------------------------------------------------------------------
// Fused K+V projection GEMM: Bt = [wkT ; wvT] contiguous [2048][4096];
// fp32 output splits block-uniformly at column 1024 into Ck / Cv.
// ---------------------------------------------------------------------------
__global__ __launch_bounds__(256)
void gemm_kv(const unsigned short* __restrict__ A,   // [M][K] bf16
             const unsigned short* __restrict__ Bt,  // [2048][K] bf16
             float* __restrict__ Ck,                 // [M][1024] fp32
             float* __restrict__ Cv,                 // [M][1024] fp32
             int M, int K) {
    __shared__ unsigned short As[128 * 32];
    __shared__ unsigned short Bs[128 * 32];
    const int tid  = threadIdx.x;
    const int lane = tid & 63;
    const int wave = tid >> 6;
    const int l16  = lane & 15;
    const int quad = lane >> 4;
    const int tileM = blockIdx.x * 128, tileN = blockIdx.y * 128;
    const int waveM = (wave >> 1) * 64, waveN = (wave & 1) * 64;

    floatx4 acc[4][4] = {};
    const int r0 = tid >> 2, ko = (tid & 3) * 8;

    for (int k0 = 0; k0 < K; k0 += 32) {
        for (int p = 0; p < 2; ++p) {
            const int idx = p * 256 + tid;
            const int row = r0 + p * 64;
            gload_lds16(A  + (size_t)(tileM + row) * K + k0 + ko, &As[idx * 8]);
            gload_lds16(Bt + (size_t)(tileN + row) * K + k0 + ko, &Bs[idx * 8]);
        }
        __syncthreads();
        bf16x8 af[4], bfr[4];
        for (int i = 0; i < 4; ++i) {
            af[i]  = *(const bf16x8*)&As[(waveM + i * 16 + l16) * 32 + quad * 8];
            bfr[i] = *(const bf16x8*)&Bs[(waveN + i * 16 + l16) * 32 + quad * 8];
        }
        for (int mi = 0; mi < 4; ++mi)
            for (int ni = 0; ni < 4; ++ni)
                acc[mi][ni] = __builtin_amdgcn_mfma_f32_16x16x32_bf16(
                    af[mi], bfr[ni], acc[mi][ni], 0, 0, 0);
        __syncthreads();
    }
    // block-uniform output split at col 1024
    float* const Cd = (tileN < NKV_ * HD_) ? Ck : Cv;
    const int colBase = tileN < NKV_ * HD_ ? tileN : tileN - NKV_ * HD_;
    for (int mi = 0; mi < 4; ++mi)
        for (int r = 0; r < 4; ++r) {
            const int row = tileM + waveM + mi * 16 + quad * 4 + r;
            for (int ni = 0; ni < 4; ++ni) {
                const int col = colBase + waveN + ni * 16 + l16;
                Cd[(size_t)row * (NKV_ * HD_) + col] = acc[mi][ni][r];
            }
        }
}

// ---------------------------------------------------------------------------
// RoPE:
//  Q: in-place on bf16 [b][s][h][d]
//  K: xk fp32 [b][s][g][d] -> new_k fp32 (output) + kb bf16 [b][g][s][d]
//  V: new_v fp32 (already final output) -> vtb bf16 transposed [b][g][d][s]
// ---------------------------------------------------------------------------
__global__ __launch_bounds__(256)
void rope2(unsigned short* __restrict__ qio, const float* __restrict__ xk,
           const float* __restrict__ nv, const float* __restrict__ fc,
           unsigned short* __restrict__ kb, unsigned short* __restrict__ vtb,
           float* __restrict__ new_k) {
    const long long QP = (long long)B_ * S_ * NH_ * (HD_ / 2);   // 8388608
    const long long KP = (long long)B_ * S_ * NKV_ * (HD_ / 2);  // 2097152
    const long long idx = (long long)blockIdx.x * 256 + threadIdx.x;
    if (idx < QP) {
        const int d2 = (int)(idx & 63);
        const long long rh = idx >> 6;                 // (b*S+s)*NH + h
        const int s = (int)((rh / NH_) % S_);
        const ushort2 u = *(const ushort2*)(qio + idx * 2);
        const float xr = bf2f(u.x), xi = bf2f(u.y);
        const float cs = fc[((size_t)s * 64 + d2) * 2];
        const float sn = fc[((size_t)s * 64 + d2) * 2 + 1];
        *(ushort2*)(qio + idx * 2) =
            make_ushort2(f2bf(xr * cs - xi * sn), f2bf(xr * sn + xi * cs));
    } else if (idx < QP + KP) {
        const long long e = idx - QP;
        const int d2 = (int)(e & 63);
        const long long rh = e >> 6;                   // (b*S+s)*NKV + g
        const int g = (int)(rh & (NKV_ - 1));
        const long long row = rh >> 3;                 // b*S + s
        const int b = (int)(row / S_), s = (int)(row % S_);
        const float2 v = *(const float2*)(xk + e * 2);
        const float cs = fc[((size_t)s * 64 + d2) * 2];
        const float sn = fc[((size_t)s * 64 + d2) * 2 + 1];
        const float orr = v.x * cs - v.y * sn;
        const float oii = v.x * sn + v.y * cs;
        *(float2*)(new_k + e * 2) = make_float2(orr, oii);
        const size_t kbi = ((size_t)(b * NKV_ + g) * S_ + s) * HD_ + d2 * 2;
        *(ushort2*)(kb + kbi) = make_ushort2(f2bf(orr), f2bf(oii));
    } else if (idx < QP + 2 * KP) {
        const long long e = idx - QP - KP;
        const float2 v = *(const float2*)(nv + e * 2);
        const long long fe = e * 2;
        const int c = (int)(fe & (HD_ - 1));
        const long long rh = fe >> 7;                  // (b*S+s)*NKV + g
        const int g = (int)(rh & (NKV_ - 1));
        const long long row = rh >> 3;
        const int b = (int)(row / S_), s = (int)(row % S_);
        const size_t base = ((size_t)(b * NKV_ + g) * HD_ + c) * S_ + s;
        vtb[base]      = f2bf(v.x);
        vtb[base + S_] = f2bf(v.y);
    }
}

// ---------------------------------------------------------------------------
// Flash attention v7: v4b LDS layouts UNCHANGED (verified r3/r8/r9), but each
// wave now owns TWO q-tiles (qt and qt+4; grid halves to 1024 blocks).
//  - kf K-fragments loaded once, feed both q-tiles' QK^T (K DS reads halved)
//  - staging/barrier cost amortized over 2x MFMA work; K/V L2 refetch halved
//  - P LDS region SHARED sequentially (softmaxA->PVA->softmaxB->PVB): LDS
//    stays 73KB -> 2 blocks/CU. WAR on P is safe: per-wave DS ops execute
//    in order and the compiler orders aliasing LDS accesses; PV-A's pf reads
//    are register-consumed (compiler lgkmcnt) before softmax-B writes issue.
// ---------------------------------------------------------------------------
__global__ __launch_bounds__(256)
void flash_attn(const unsigned short* __restrict__ qb,
                const unsigned short* __restrict__ kb,
                const unsigned short* __restrict__ vtb,
                unsigned short* __restrict__ ctxb) {
    __shared__ unsigned short Ks[2][64 * 128];   // [key][d]   swizzled, 32KB
    __shared__ unsigned short Vs[2][128 * 64];   // [d][key]   swizzled, 32KB
    __shared__ unsigned short Plds[4][16 * 72];  // per-wave P (shared A/B), 9KB
    const int tid  = threadIdx.x;
    const int wave = tid >> 6, lane = tid & 63;
    const int l16  = lane & 15, quad = lane >> 4;
    const int bi  = blockIdx.x;
    const int qt8 = bi & (S_ / 128 - 1);    // 0..15 (128 q-rows per block)
    const int bh  = bi >> 4;
    const int h = bh & (NH_ - 1), b = bh >> 5;
    const int g = h >> 2;                   // NREP_=4
    const int qtA = qt8 * 8 + wave;         // wave's first q-tile
    const int qtB = qtA + 4;                // wave's second q-tile
    const float sc2 = 0.12754857629633723f;  // 1/sqrt(128) * log2(e)

    const unsigned short* kbase = kb  + (size_t)(b * NKV_ + g) * S_ * HD_;
    const unsigned short* vbase = vtb + (size_t)(b * NKV_ + g) * HD_ * S_;

    bf16x8 qfA[4], qfB[4];
    {
        const unsigned short* qpA =
            qb + ((size_t)(b * S_ + qtA * 16 + l16) * NH_ + h) * HD_;
        const unsigned short* qpB =
            qb + ((size_t)(b * S_ + qtB * 16 + l16) * NH_ + h) * HD_;
        for (int c = 0; c < 4; ++c) {
            qfA[c] = *(const bf16x8*)(qpA + c * 32 + quad * 8);
            qfB[c] = *(const bf16x8*)(qpB + c * 32 + quad * 8);
        }
    }

    float mA[4], lA[4], mB[4], lB[4];
    for (int r = 0; r < 4; ++r) { mA[r] = -1e30f; lA[r] = 0.f;
                                  mB[r] = -1e30f; lB[r] = 0.f; }
    floatx4 oA[8] = {}, oB[8] = {};
    unsigned short* pw = &Plds[wave][0];

    // cooperative stage of one 64-key K/V tile pair (32KB) into buffer `buf`
    auto stage = [&](int buf, int kt) {
        for (int rnd = 0; rnd < 4; ++rnd) {           // K: 1024 x 16B chunks
            const int ci = rnd * 256 + tid;
            const int row = ci >> 4, c = ci & 15;     // 16 chunks / 256B row
            gload_lds16(kbase + (size_t)(kt + row) * HD_ + (c ^ (row & 15)) * 8,
                        &Ks[buf][ci * 8]);
        }
        for (int rnd = 0; rnd < 4; ++rnd) {           // V: 1024 x 16B chunks
            const int ci = rnd * 256 + tid;
            const int row = ci >> 3, c = ci & 7;      // 8 chunks / 128B row
            gload_lds16(vbase + (size_t)row * S_ + kt + (c ^ (row & 7)) * 8,
                        &Vs[buf][ci * 8]);
        }
    };

    stage(0, 0);
    __syncthreads();   // emits vmcnt(0)+lgkmcnt(0) drain before s_barrier

    int cur = 0;
    for (int kt = 0; kt < S_; kt += 64) {
        if (kt + 64 < S_) stage(cur ^ 1, kt + 64);    // prefetch || compute
        // ---- scores for BOTH q-tiles: kf loaded once, used twice
        floatx4 sA[4] = {}, sB[4] = {};
        __builtin_amdgcn_s_setprio(1);
        for (int t = 0; t < 4; ++t) {
            const int row = t * 16 + l16;
            const char* kp = (const char*)&Ks[cur][row * 128];
            for (int c = 0; c < 4; ++c) {
                const bf16x8 kf = *(const bf16x8*)
                    (kp + ((c * 64 + quad * 16) ^ (l16 << 4)));   // row&15 == l16
                sA[t] = __builtin_amdgcn_mfma_f32_16x16x32_bf16(qfA[c], kf, sA[t], 0, 0, 0);
                sB[t] = __builtin_amdgcn_mfma_f32_16x16x32_bf16(qfB[c], kf, sB[t], 0, 0, 0);
            }
        }
        __builtin_amdgcn_s_setprio(0);

        // ---- softmax + PV for one q-tile (P region reused sequentially)
        auto smpv = [&](floatx4 (&sacc)[4], float (&m_i)[4], float (&l_p)[4],
                        floatx4 (&oacc)[8]) {
            float sv[4][4], mx[4];
            for (int r = 0; r < 4; ++r) {
                const float s0 = sacc[0][r] * sc2, s1 = sacc[1][r] * sc2;
                const float s2 = sacc[2][r] * sc2, s3 = sacc[3][r] * sc2;
                sv[0][r] = s0; sv[1][r] = s1; sv[2][r] = s2; sv[3][r] = s3;
                mx[r] = rowmax16(fmaxf(fmaxf(s0, s1), fmaxf(s2, s3)));
            }
            const bool ok = (mx[0] <= m_i[0] + 8.f) && (mx[1] <= m_i[1] + 8.f) &&
                            (mx[2] <= m_i[2] + 8.f) && (mx[3] <= m_i[3] + 8.f);
            if (__all(ok)) {
                for (int r = 0; r < 4; ++r) {
                    const float e0 = __builtin_amdgcn_exp2f(sv[0][r] - m_i[r]);
                    const float e1 = __builtin_amdgcn_exp2f(sv[1][r] - m_i[r]);
                    const float e2 = __builtin_amdgcn_exp2f(sv[2][r] - m_i[r]);
                    const float e3 = __builtin_amdgcn_exp2f(sv[3][r] - m_i[r]);
                    l_p[r] += (e0 + e1) + (e2 + e3);
                    const int ro = (quad * 4 + r) * 72 + l16;
                    const unsigned int p01 = cvt_pk_bf16(e0, e1);
                    const unsigned int p23 = cvt_pk_bf16(e2, e3);
                    pw[ro]      = (unsigned short)p01;
                    pw[ro + 16] = (unsigned short)(p01 >> 16);
                    pw[ro + 32] = (unsigned short)p23;
                    pw[ro + 48] = (unsigned short)(p23 >> 16);
                }
            } else {
                float alpha[4];
                for (int r = 0; r < 4; ++r) {
                    const float mnew = fmaxf(m_i[r], mx[r]);
                    const float a  = __builtin_amdgcn_exp2f(m_i[r] - mnew);
                    const float e0 = __builtin_amdgcn_exp2f(sv[0][r] - mnew);
                    const float e1 = __builtin_amdgcn_exp2f(sv[1][r] - mnew);
                    const float e2 = __builtin_amdgcn_exp2f(sv[2][r] - mnew);
                    const float e3 = __builtin_amdgcn_exp2f(sv[3][r] - mnew);
                    l_p[r] = l_p[r] * a + (e0 + e1) + (e2 + e3);
                    m_i[r] = mnew;
                    alpha[r] = a;
                    const int ro = (quad * 4 + r) * 72 + l16;
                    const unsigned int p01 = cvt_pk_bf16(e0, e1);
                    const unsigned int p23 = cvt_pk_bf16(e2, e3);
                    pw[ro]      = (unsigned short)p01;
                    pw[ro + 16] = (unsigned short)(p01 >> 16);
                    pw[ro + 32] = (unsigned short)p23;
                    pw[ro + 48] = (unsigned short)(p23 >> 16);
                }
                for (int f = 0; f < 8; ++f)
                    for (int r = 0; r < 4; ++r) oacc[f][r] *= alpha[r];
            }
            // drain our DS writes (per-wave region; no cross-wave sharing)
            asm volatile("s_waitcnt lgkmcnt(0)" ::: "memory");
            __builtin_amdgcn_s_setprio(1);
            for (int t2 = 0; t2 < 2; ++t2) {
                const bf16x8 pf = *(const bf16x8*)&pw[l16 * 72 + t2 * 32 + quad * 8];
                for (int f = 0; f < 8; ++f) {
                    const int row = f * 16 + l16;
                    const bf16x8 vf = *(const bf16x8*)((const char*)&Vs[cur][row * 64]
                                       + ((t2 * 64 + quad * 16) ^ ((l16 & 7) << 4)));
                    oacc[f] = __builtin_amdgcn_mfma_f32_16x16x32_bf16(pf, vf, oacc[f], 0, 0, 0);
                }
            }
            __builtin_amdgcn_s_setprio(0);
        };
        smpv(sA, mA, lA, oA);
        smpv(sB, mB, lB, oB);

        __syncthreads();  // drains prefetch vmcnt + guards buffer swap
        cur ^= 1;
    }
    // ---- epilogue: reduce deferred l partials, store both q-tiles
    for (int r = 0; r < 4; ++r) {
        float l = lA[r];
        for (int off = 1; off < 16; off <<= 1) l += __shfl_xor(l, off);
        const float inv = 1.0f / l;
        const int srow = qtA * 16 + quad * 4 + r;
        unsigned short* cp = ctxb + ((size_t)(b * S_ + srow) * NH_ + h) * HD_ + l16;
        for (int f = 0; f < 8; ++f) cp[f * 16] = f2bf(oA[f][r] * inv);
    }
    for (int r = 0; r < 4; ++r) {
        float l = lB[r];
        for (int off = 1; off < 16; off <<= 1) l += __shfl_xor(l, off);
        const float inv = 1.0f / l;
        const int srow = qtB * 16 + quad * 4 + r;
        unsigned short* cp = ctxb + ((size_t)(b * S_ + srow) * NH_ + h) * HD_ + l16;
        for (int f = 0; f < 8; ++f) cp[f * 16] = f2bf(oB[f][r] * inv);
    }
}

// ---------------------------------------------------------------------------
extern "C" void kernel_launch(void* const* d_in, const int* in_sizes, int n_in,
                              void* d_out, int out_size, void* d_ws, size_t ws_size,
                              hipStream_t stream) {
    const float* x  = (const float*)d_in[0];
    const float* fc = (const float*)d_in[1];
    const float* wq = (const float*)d_in[2];
    const float* wk = (const float*)d_in[3];
    const float* wv = (const float*)d_in[4];
    const float* wo = (const float*)d_in[5];

    float* out   = (float*)d_out;                         // [B,S,DIM]
    float* new_k = out + (size_t)B_ * S_ * NH_ * HD_;     // [B,S,NKV,HD]
    float* new_v = new_k + (size_t)B_ * S_ * NKV_ * HD_;  // [B,S,NKV,HD]

    // workspace layout (144 MB total). wkT+wvT are ADJACENT -> viewed from
    // wkT they form a contiguous [2048][4096] B^T for the fused KV GEMM.
    char* ws = (char*)d_ws;
    unsigned short* xb   = (unsigned short*)(ws);                  // 32MB (later ctxb)
    unsigned short* wqT  = (unsigned short*)(ws + (32ull  << 20)); // 32MB (later woT)
    unsigned short* wkT  = (unsigned short*)(ws + (64ull  << 20)); //  8MB
    unsigned short* wvT  = (unsigned short*)(ws + (72ull  << 20)); //  8MB
    unsigned short* xqb  = (unsigned short*)(ws + (80ull  << 20)); // 32MB (rope in-place)
    float*          xk   = (float*)         (ws + (112ull << 20)); // 16MB
    unsigned short* kbuf = (unsigned short*)(ws + (128ull << 20)); //  8MB
    unsigned short* vtb  = (unsigned short*)(ws + (136ull << 20)); //  8MB  (end 144MB)
    unsigned short* ctxb = xb;   // xb dead after QKV GEMMs
    unsigned short* woT  = wqT;  // wqT dead after Q GEMM

    const int M = B_ * S_;  // 4096
    dim3 blk(256);

    // ---- pre-convert activations + weights to bf16 (weights transposed [N][K])
    convert_bf16<<<(int)(((size_t)M * DIM_ / 4 + 255) / 256), blk, 0, stream>>>(
        x, xb, (long long)M * DIM_);
    transpose_conv<<<dim3(DIM_ / 32, DIM_ / 32), blk, 0, stream>>>(wq, wqT, DIM_, DIM_);
    transpose_conv<<<dim3((NKV_ * HD_) / 32, DIM_ / 32), blk, 0, stream>>>(wk, wkT, DIM_, NKV_ * HD_);
    transpose_conv<<<dim3((NKV_ * HD_) / 32, DIM_ / 32), blk, 0, stream>>>(wv, wvT, DIM_, NKV_ * HD_);

    // ---- projections: Q (N=4096) + fused K|V (N=2048, output split)
    gemm_bt<true ><<<dim3(M / 128, (NH_  * HD_) / 128), blk, 0, stream>>>(xb, wqT, xqb, M, NH_ * HD_, DIM_);
    gemm_kv<<<dim3(M / 128, (2 * NKV_ * HD_) / 128), blk, 0, stream>>>(xb, wkT, xk, new_v, M, DIM_);

    // wo transpose after Q-GEMM (reuses wqT region; stream-ordered)
    transpose_conv<<<dim3(DIM_ / 32, DIM_ / 32), blk, 0, stream>>>(wo, woT, DIM_, DIM_);

    // ---- RoPE + layout conversion
    const long long totalPairs = (long long)B_ * S_ * (HD_ / 2) * (NH_ + 2 * NKV_);
    rope2<<<(int)((totalPairs + 255) / 256), blk, 0, stream>>>(
        xqb, xk, new_v, fc, kbuf, vtb, new_k);

    // ---- attention (2 q-tiles per wave -> 1024 blocks)
    flash_attn<<<B_ * NH_ * (S_ / 128), blk, 0, stream>>>(xqb, kbuf, vtb, ctxb);

    // ---- output projection
    gemm_bt<false><<<dim3(M / 128, DIM_ / 128), blk, 0, stream>>>(ctxb, woT, out, M, DIM_, DIM_);
}

// Round 11
// 1035.571 us; speedup vs baseline: 1.1236x; 1.1236x over previous
//
#include <hip/hip_runtime.h>
#include <hip/hip_bf16.h>
#include <math.h>

#define B_    2
#define S_    2048
#define DIM_  4096
#define NH_   32
#define NKV_  8
#define HD_   128
#define NREP_ 4
// NOTE: KVB=32 flash_attn restructure failed correctness 3x. Do not retry blind.
// NOTE: T1 XCD swizzle on gemm_bt REGRESSED +47us (r8). Reverted.
// NOTE: 2-qtile-per-wave flash REGRESSED 297->387us (r10: occupancy 22->11.6%,
// VGPR 92->140, FETCH unchanged -- K/V refetch was already L2-absorbed). Reverted.
// r9 anchor: flash v4b = 297us; fused KV GEMM saved ~115us; total 1069.

typedef __attribute__((ext_vector_type(8))) short bf16x8;   // 8 bf16 in 4 VGPRs
typedef __attribute__((ext_vector_type(4))) float floatx4;  // MFMA C/D frag

__device__ __forceinline__ unsigned short f2bf(float f) {
    unsigned int u = __float_as_uint(f);
    unsigned int r = (u + 0x7FFFu + ((u >> 16) & 1u)) >> 16;  // RNE
    return (unsigned short)r;
}
__device__ __forceinline__ float bf2f(unsigned short u) {
    return __uint_as_float((unsigned int)u << 16);
}
// packed f32x2 -> bf16x2 (RNE), single HW op; no builtin on gfx950
__device__ __forceinline__ unsigned int cvt_pk_bf16(float lo, float hi) {
    unsigned int r;
    asm("v_cvt_pk_bf16_f32 %0, %1, %2" : "=v"(r) : "v"(lo), "v"(hi));
    return r;
}
// max-reduce over each 16-lane row via DPP row_ror 1,2,4,8 (VALU-only,
// no DS pipe). dpp_ctrl args MUST be literal constants (clang sema).
__device__ __forceinline__ float rowmax16(float x) {
    int t;
    t = __builtin_amdgcn_mov_dpp(__float_as_int(x), 0x121, 0xf, 0xf, true);
    x = fmaxf(x, __int_as_float(t));
    t = __builtin_amdgcn_mov_dpp(__float_as_int(x), 0x122, 0xf, 0xf, true);
    x = fmaxf(x, __int_as_float(t));
    t = __builtin_amdgcn_mov_dpp(__float_as_int(x), 0x124, 0xf, 0xf, true);
    x = fmaxf(x, __int_as_float(t));
    t = __builtin_amdgcn_mov_dpp(__float_as_int(x), 0x128, 0xf, 0xf, true);
    x = fmaxf(x, __int_as_float(t));
    return x;
}
// async global->LDS, 16B per lane; LDS dst = readfirstlane(base) + lane*16
__device__ __forceinline__ void gload_lds16(const unsigned short* g, unsigned short* l) {
    __builtin_amdgcn_global_load_lds(
        (const __attribute__((address_space(1))) void*)g,
        (__attribute__((address_space(3))) void*)l, 16, 0, 0);
}

// ---------------------------------------------------------------------------
// fp32 -> bf16 elementwise (same layout), n % 4 == 0
// ---------------------------------------------------------------------------
__global__ __launch_bounds__(256)
void convert_bf16(const float* __restrict__ in, unsigned short* __restrict__ out,
                  long long n) {
    long long i = ((long long)blockIdx.x * 256 + threadIdx.x) * 4;
    if (i >= n) return;
    const float4 v = *(const float4*)(in + i);
    ushort4 o;
    o.x = f2bf(v.x); o.y = f2bf(v.y); o.z = f2bf(v.z); o.w = f2bf(v.w);
    *(ushort4*)(out + i) = o;
}

// ---------------------------------------------------------------------------
// W fp32 [K][N] -> Wt bf16 [N][K]  (tiled 32x32 transpose, 256 threads)
// ---------------------------------------------------------------------------
__global__ __launch_bounds__(256)
void transpose_conv(const float* __restrict__ W, unsigned short* __restrict__ Wt,
                    int K, int N) {
    __shared__ unsigned short t[32][33];
    const int tx = threadIdx.x & 31, ty = threadIdx.x >> 5;  // ty 0..7
    const int n0 = blockIdx.x * 32, k0 = blockIdx.y * 32;
    for (int i = 0; i < 4; ++i)
        t[ty + i * 8][tx] = f2bf(W[(size_t)(k0 + ty + i * 8) * N + n0 + tx]);
    __syncthreads();
    for (int i = 0; i < 4; ++i)
        Wt[(size_t)(n0 + ty + i * 8) * K + k0 + tx] = t[tx][ty + i * 8];
}

// ---------------------------------------------------------------------------
// GEMM (m97 structure): C[M][N] = A[M][K] @ Bt[N][K]^T, bf16 in, fp32 acc.
// 128x128 tile, BK=32, 256 threads (4 waves, 64x64 each, 4x4 frags).
// Staging via global_load_lds width=16 into UNPADDED LDS (HW layout rule).
// ---------------------------------------------------------------------------
template<bool OUT_BF16>
__global__ __launch_bounds__(256)
void gemm_bt(const unsigned short* __restrict__ A,   // [M][K] bf16
             const unsigned short* __restrict__ Bt,  // [N][K] bf16
             void* __restrict__ C, int M, int N, int K) {
    __shared__ unsigned short As[128 * 32];
    __shared__ unsigned short Bs[128 * 32];
    const int tid  = threadIdx.x;
    const int lane = tid & 63;
    const int wave = tid >> 6;
    const int l16  = lane & 15;
    const int quad = lane >> 4;
    const int tileM = blockIdx.x * 128, tileN = blockIdx.y * 128;
    const int waveM = (wave >> 1) * 64, waveN = (wave & 1) * 64;

    floatx4 acc[4][4] = {};

    // staging geometry: idx = p*256+tid; 16B/lane; row = idx/4 (32 elems/row)
    const int r0 = tid >> 2, ko = (tid & 3) * 8;

    for (int k0 = 0; k0 < K; k0 += 32) {
        for (int p = 0; p < 2; ++p) {
            const int idx = p * 256 + tid;
            const int row = r0 + p * 64;
            gload_lds16(A  + (size_t)(tileM + row) * K + k0 + ko, &As[idx * 8]);
            gload_lds16(Bt + (size_t)(tileN + row) * K + k0 + ko, &Bs[idx * 8]);
        }
        __syncthreads();
        bf16x8 af[4], bfr[4];
        for (int i = 0; i < 4; ++i) {
            af[i]  = *(const bf16x8*)&As[(waveM + i * 16 + l16) * 32 + quad * 8];
            bfr[i] = *(const bf16x8*)&Bs[(waveN + i * 16 + l16) * 32 + quad * 8];
        }
        for (int mi = 0; mi < 4; ++mi)
            for (int ni = 0; ni < 4; ++ni)
                acc[mi][ni] = __builtin_amdgcn_mfma_f32_16x16x32_bf16(
                    af[mi], bfr[ni], acc[mi][ni], 0, 0, 0);
        __syncthreads();
    }
    // epilogue: C/D layout col=lane&15, row=quad*4+reg
    for (int mi = 0; mi < 4; ++mi)
        for (int r = 0; r < 4; ++r) {
            const int row = tileM + waveM + mi * 16 + quad * 4 + r;
            for (int ni = 0; ni < 4; ++ni) {
                const int col = tileN + waveN + ni * 16 + l16;
                if (OUT_BF16)
                    ((unsigned short*)C)[(size_t)row * N + col] = f2bf(acc[mi][ni][r]);
                else
                    ((float*)C)[(size_t)row * N + col] = acc[mi][ni][r];
            }
        }
}

// ---------------------------------------------------------------------------
// Fused Q+K+V projection GEMM: Bt = [wqT ; wkT ; wvT] contiguous [6144][4096].
// Output splits block-uniformly by tileN:
//   [0,4096)    -> xqb  bf16 [M][4096]
//   [4096,5120) -> xk   fp32 [M][1024]
//   [5120,6144) -> nv   fp32 [M][1024]
// One 1536-block launch (6 blocks/CU) replaces Q (1024 blk) + KV (512 blk).
// ---------------------------------------------------------------------------
__global__ __launch_bounds__(256)
void gemm_qkv(const unsigned short* __restrict__ A,   // [M][K] bf16
              const unsigned short* __restrict__ Bt,  // [6144][K] bf16
              unsigned short* __restrict__ Cq,        // [M][4096] bf16
              float* __restrict__ Ck,                 // [M][1024] fp32
              float* __restrict__ Cv,                 // [M][1024] fp32
              int M, int K) {
    __shared__ unsigned short As[128 * 32];
    __shared__ unsigned short Bs[128 * 32];
    const int tid  = threadIdx.x;
    const int lane = tid & 63;
    const int wave = tid >> 6;
    const int l16  = lane & 15;
    const int quad = lane >> 4;
    const int tileM = blockIdx.x * 128, tileN = blockIdx.y * 128;
    const int waveM = (wave >> 1) * 64, waveN = (wave & 1) * 64;

    floatx4 acc[4][4] = {};
    const int r0 = tid >> 2, ko = (tid & 3) * 8;

    for (int k0 = 0; k0 < K; k0 += 32) {
        for (int p = 0; p < 2; ++p) {
            const int idx = p * 256 + tid;
            const int row = r0 + p * 64;
            gload_lds16(A  + (size_t)(tileM + row) * K + k0 + ko, &As[idx * 8]);
            gload_lds16(Bt + (size_t)(tileN + row) * K + k0 + ko, &Bs[idx * 8]);
        }
        __syncthreads();
        bf16x8 af[4], bfr[4];
        for (int i = 0; i < 4; ++i) {
            af[i]  = *(const bf16x8*)&As[(waveM + i * 16 + l16) * 32 + quad * 8];
            bfr[i] = *(const bf16x8*)&Bs[(waveN + i * 16 + l16) * 32 + quad * 8];
        }
        for (int mi = 0; mi < 4; ++mi)
            for (int ni = 0; ni < 4; ++ni)
                acc[mi][ni] = __builtin_amdgcn_mfma_f32_16x16x32_bf16(
                    af[mi], bfr[ni], acc[mi][ni], 0, 0, 0);
        __syncthreads();
    }
    // block-uniform 3-way output split
    if (tileN < NH_ * HD_) {
        for (int mi = 0; mi < 4; ++mi)
            for (int r = 0; r < 4; ++r) {
                const int row = tileM + waveM + mi * 16 + quad * 4 + r;
                for (int ni = 0; ni < 4; ++ni) {
                    const int col = tileN + waveN + ni * 16 + l16;
                    Cq[(size_t)row * (NH_ * HD_) + col] = f2bf(acc[mi][ni][r]);
                }
            }
    } else {
        const bool isK = tileN < NH_ * HD_ + NKV_ * HD_;
        float* const Cd = isK ? Ck : Cv;
        const int colBase = tileN - (isK ? NH_ * HD_ : NH_ * HD_ + NKV_ * HD_);
        for (int mi = 0; mi < 4; ++mi)
            for (int r = 0; r < 4; ++r) {
                const int row = tileM + waveM + mi * 16 + quad * 4 + r;
                for (int ni = 0; ni < 4; ++ni) {
                    const int col = colBase + waveN + ni * 16 + l16;
                    Cd[(size_t)row * (NKV_ * HD_) + col] = acc[mi][ni][r];
                }
            }
    }
}

// ---------------------------------------------------------------------------
// RoPE:
//  Q: in-place on bf16 [b][s][h][d]
//  K: xk fp32 [b][s][g][d] -> new_k fp32 (output) + kb bf16 [b][g][s][d]
//  V: new_v fp32 (already final output) -> vtb bf16 transposed [b][g][d][s]
// ---------------------------------------------------------------------------
__global__ __launch_bounds__(256)
void rope2(unsigned short* __restrict__ qio, const float* __restrict__ xk,
           const float* __restrict__ nv, const float* __restrict__ fc,
           unsigned short* __restrict__ kb, unsigned short* __restrict__ vtb,
           float* __restrict__ new_k) {
    const long long QP = (long long)B_ * S_ * NH_ * (HD_ / 2);   // 8388608
    const long long KP = (long long)B_ * S_ * NKV_ * (HD_ / 2);  // 2097152
    const long long idx = (long long)blockIdx.x * 256 + threadIdx.x;
    if (idx < QP) {
        const int d2 = (int)(idx & 63);
        const long long rh = idx >> 6;                 // (b*S+s)*NH + h
        const int s = (int)((rh / NH_) % S_);
        const ushort2 u = *(const ushort2*)(qio + idx * 2);
        const float xr = bf2f(u.x), xi = bf2f(u.y);
        const float cs = fc[((size_t)s * 64 + d2) * 2];
        const float sn = fc[((size_t)s * 64 + d2) * 2 + 1];
        *(ushort2*)(qio + idx * 2) =
            make_ushort2(f2bf(xr * cs - xi * sn), f2bf(xr * sn + xi * cs));
    } else if (idx < QP + KP) {
        const long long e = idx - QP;
        const int d2 = (int)(e & 63);
        const long long rh = e >> 6;                   // (b*S+s)*NKV + g
        const int g = (int)(rh & (NKV_ - 1));
        const long long row = rh >> 3;                 // b*S + s
        const int b = (int)(row / S_), s = (int)(row % S_);
        const float2 v = *(const float2*)(xk + e * 2);
        const float cs = fc[((size_t)s * 64 + d2) * 2];
        const float sn = fc[((size_t)s * 64 + d2) * 2 + 1];
        const float orr = v.x * cs - v.y * sn;
        const float oii = v.x * sn + v.y * cs;
        *(float2*)(new_k + e * 2) = make_float2(orr, oii);
        const size_t kbi = ((size_t)(b * NKV_ + g) * S_ + s) * HD_ + d2 * 2;
        *(ushort2*)(kb + kbi) = make_ushort2(f2bf(orr), f2bf(oii));
    } else if (idx < QP + 2 * KP) {
        const long long e = idx - QP - KP;
        const float2 v = *(const float2*)(nv + e * 2);
        const long long fe = e * 2;
        const int c = (int)(fe & (HD_ - 1));
        const long long rh = fe >> 7;                  // (b*S+s)*NKV + g
        const int g = (int)(rh & (NKV_ - 1));
        const long long row = rh >> 3;
        const int b = (int)(row / S_), s = (int)(row % S_);
        const size_t base = ((size_t)(b * NKV_ + g) * HD_ + c) * S_ + s;
        vtb[base]      = f2bf(v.x);
        vtb[base + S_] = f2bf(v.y);
    }
}

// ---------------------------------------------------------------------------
// Flash attention v4b (VERIFIED r3/r8/r9): LDS-staged K/V (double-buffered,
// swizzled), KVB=64. Deferred l-sum, defer-max (T13), exp2-domain, DPP
// rowmax, cvt_pk P->bf16, setprio around MFMA clusters.
// ---------------------------------------------------------------------------
__global__ __launch_bounds__(256)
void flash_attn(const unsigned short* __restrict__ qb,
                const unsigned short* __restrict__ kb,
                const unsigned short* __restrict__ vtb,
                unsigned short* __restrict__ ctxb) {
    __shared__ unsigned short Ks[2][64 * 128];   // [key][d]   swizzled, 32KB
    __shared__ unsigned short Vs[2][128 * 64];   // [d][key]   swizzled, 32KB
    __shared__ unsigned short Plds[4][16 * 72];  // per-wave P, 9KB
    const int tid  = threadIdx.x;
    const int wave = tid >> 6, lane = tid & 63;
    const int l16  = lane & 15, quad = lane >> 4;
    const int bi  = blockIdx.x;
    const int qt4 = bi & (S_ / 64 - 1);     // 0..31
    const int bh  = bi >> 5;
    const int h = bh & (NH_ - 1), b = bh >> 5;
    const int g = h >> 2;                   // NREP_=4
    const int qt = qt4 * 4 + wave;
    const float sc2 = 0.12754857629633723f;  // 1/sqrt(128) * log2(e)

    const unsigned short* kbase = kb  + (size_t)(b * NKV_ + g) * S_ * HD_;
    const unsigned short* vbase = vtb + (size_t)(b * NKV_ + g) * HD_ * S_;

    bf16x8 qf[4];
    {
        const unsigned short* qp =
            qb + ((size_t)(b * S_ + qt * 16 + l16) * NH_ + h) * HD_;
        for (int c = 0; c < 4; ++c) qf[c] = *(const bf16x8*)(qp + c * 32 + quad * 8);
    }

    float m_i[4], l_p[4];
    for (int r = 0; r < 4; ++r) { m_i[r] = -1e30f; l_p[r] = 0.f; }
    floatx4 oacc[8] = {};
    unsigned short* pw = &Plds[wave][0];

    // cooperative stage of one 64-key K/V tile pair (32KB) into buffer `buf`
    auto stage = [&](int buf, int kt) {
        for (int rnd = 0; rnd < 4; ++rnd) {           // K: 1024 x 16B chunks
            const int ci = rnd * 256 + tid;
            const int row = ci >> 4, c = ci & 15;     // 16 chunks / 256B row
            gload_lds16(kbase + (size_t)(kt + row) * HD_ + (c ^ (row & 15)) * 8,
                        &Ks[buf][ci * 8]);
        }
        for (int rnd = 0; rnd < 4; ++rnd) {           // V: 1024 x 16B chunks
            const int ci = rnd * 256 + tid;
            const int row = ci >> 3, c = ci & 7;      // 8 chunks / 128B row
            gload_lds16(vbase + (size_t)row * S_ + kt + (c ^ (row & 7)) * 8,
                        &Vs[buf][ci * 8]);
        }
    };

    stage(0, 0);
    __syncthreads();   // emits vmcnt(0)+lgkmcnt(0) drain before s_barrier

    int cur = 0;
    for (int kt = 0; kt < S_; kt += 64) {
        if (kt + 64 < S_) stage(cur ^ 1, kt + 64);    // prefetch || compute
        // ---- scores: 16 q-rows x 64 keys from LDS (4 indep MFMA chains)
        floatx4 sacc[4] = {};
        __builtin_amdgcn_s_setprio(1);
        for (int t = 0; t < 4; ++t) {
            const int row = t * 16 + l16;
            const char* kp = (const char*)&Ks[cur][row * 128];
            for (int c = 0; c < 4; ++c) {
                const bf16x8 kf = *(const bf16x8*)
                    (kp + ((c * 64 + quad * 16) ^ (l16 << 4)));   // row&15 == l16
                sacc[t] = __builtin_amdgcn_mfma_f32_16x16x32_bf16(qf[c], kf, sacc[t], 0, 0, 0);
            }
        }
        __builtin_amdgcn_s_setprio(0);
        // ---- online softmax in exp2 domain
        float sv[4][4], mx[4];
        for (int r = 0; r < 4; ++r) {
            const float s0 = sacc[0][r] * sc2, s1 = sacc[1][r] * sc2;
            const float s2 = sacc[2][r] * sc2, s3 = sacc[3][r] * sc2;
            sv[0][r] = s0; sv[1][r] = s1; sv[2][r] = s2; sv[3][r] = s3;
            mx[r] = rowmax16(fmaxf(fmaxf(s0, s1), fmaxf(s2, s3)));
        }
        const bool ok = (mx[0] <= m_i[0] + 8.f) && (mx[1] <= m_i[1] + 8.f) &&
                        (mx[2] <= m_i[2] + 8.f) && (mx[3] <= m_i[3] + 8.f);
        if (__all(ok)) {
            // defer-max fast path: keep m_i; P bounded by 2^8; no rescale
            for (int r = 0; r < 4; ++r) {
                const float e0 = __builtin_amdgcn_exp2f(sv[0][r] - m_i[r]);
                const float e1 = __builtin_amdgcn_exp2f(sv[1][r] - m_i[r]);
                const float e2 = __builtin_amdgcn_exp2f(sv[2][r] - m_i[r]);
                const float e3 = __builtin_amdgcn_exp2f(sv[3][r] - m_i[r]);
                l_p[r] += (e0 + e1) + (e2 + e3);
                const int ro = (quad * 4 + r) * 72 + l16;
                const unsigned int p01 = cvt_pk_bf16(e0, e1);
                const unsigned int p23 = cvt_pk_bf16(e2, e3);
                pw[ro]      = (unsigned short)p01;
                pw[ro + 16] = (unsigned short)(p01 >> 16);
                pw[ro + 32] = (unsigned short)p23;
                pw[ro + 48] = (unsigned short)(p23 >> 16);
            }
        } else {
            float alpha[4];
            for (int r = 0; r < 4; ++r) {
                const float mnew = fmaxf(m_i[r], mx[r]);
                const float a  = __builtin_amdgcn_exp2f(m_i[r] - mnew);
                const float e0 = __builtin_amdgcn_exp2f(sv[0][r] - mnew);
                const float e1 = __builtin_amdgcn_exp2f(sv[1][r] - mnew);
                const float e2 = __builtin_amdgcn_exp2f(sv[2][r] - mnew);
                const float e3 = __builtin_amdgcn_exp2f(sv[3][r] - mnew);
                l_p[r] = l_p[r] * a + (e0 + e1) + (e2 + e3);
                m_i[r] = mnew;
                alpha[r] = a;
                const int ro = (quad * 4 + r) * 72 + l16;
                const unsigned int p01 = cvt_pk_bf16(e0, e1);
                const unsigned int p23 = cvt_pk_bf16(e2, e3);
                pw[ro]      = (unsigned short)p01;
                pw[ro + 16] = (unsigned short)(p01 >> 16);
                pw[ro + 32] = (unsigned short)p23;
                pw[ro + 48] = (unsigned short)(p23 >> 16);
            }
            for (int f = 0; f < 8; ++f)
                for (int r = 0; r < 4; ++r) oacc[f][r] *= alpha[r];
        }
        // drain our DS writes (per-wave region; no cross-wave sharing)
        asm volatile("s_waitcnt lgkmcnt(0)" ::: "memory");
        // ---- PV: P A-frags (2 k-chunks) x 8 HD frags, V from LDS
        __builtin_amdgcn_s_setprio(1);
        for (int t2 = 0; t2 < 2; ++t2) {
            const bf16x8 pf = *(const bf16x8*)&pw[l16 * 72 + t2 * 32 + quad * 8];
            for (int f = 0; f < 8; ++f) {
                const int row = f * 16 + l16;
                const bf16x8 vf = *(const bf16x8*)((const char*)&Vs[cur][row * 64]
                                   + ((t2 * 64 + quad * 16) ^ ((l16 & 7) << 4)));
                oacc[f] = __builtin_amdgcn_mfma_f32_16x16x32_bf16(pf, vf, oacc[f], 0, 0, 0);
            }
        }
        __builtin_amdgcn_s_setprio(0);
        __syncthreads();  // drains prefetch vmcnt + guards buffer swap
        cur ^= 1;
    }
    // ---- epilogue: reduce deferred l partials over the 16-lane row, store
    for (int r = 0; r < 4; ++r) {
        float l = l_p[r];
        for (int off = 1; off < 16; off <<= 1) l += __shfl_xor(l, off);
        const float inv = 1.0f / l;
        const int srow = qt * 16 + quad * 4 + r;
        unsigned short* cp = ctxb + ((size_t)(b * S_ + srow) * NH_ + h) * HD_ + l16;
        for (int f = 0; f < 8; ++f) cp[f * 16] = f2bf(oacc[f][r] * inv);
    }
}

// ---------------------------------------------------------------------------
extern "C" void kernel_launch(void* const* d_in, const int* in_sizes, int n_in,
                              void* d_out, int out_size, void* d_ws, size_t ws_size,
                              hipStream_t stream) {
    const float* x  = (const float*)d_in[0];
    const float* fc = (const float*)d_in[1];
    const float* wq = (const float*)d_in[2];
    const float* wk = (const float*)d_in[3];
    const float* wv = (const float*)d_in[4];
    const float* wo = (const float*)d_in[5];

    float* out   = (float*)d_out;                         // [B,S,DIM]
    float* new_k = out + (size_t)B_ * S_ * NH_ * HD_;     // [B,S,NKV,HD]
    float* new_v = new_k + (size_t)B_ * S_ * NKV_ * HD_;  // [B,S,NKV,HD]

    // workspace layout (144 MB total). wqT|wkT|wvT ADJACENT -> contiguous
    // [6144][4096] B^T for the fused QKV GEMM.
    char* ws = (char*)d_ws;
    unsigned short* xb   = (unsigned short*)(ws);                  // 32MB (later ctxb)
    unsigned short* wqT  = (unsigned short*)(ws + (32ull  << 20)); // 32MB (later woT)
    unsigned short* wkT  = (unsigned short*)(ws + (64ull  << 20)); //  8MB
    unsigned short* wvT  = (unsigned short*)(ws + (72ull  << 20)); //  8MB
    unsigned short* xqb  = (unsigned short*)(ws + (80ull  << 20)); // 32MB (rope in-place)
    float*          xk   = (float*)         (ws + (112ull << 20)); // 16MB
    unsigned short* kbuf = (unsigned short*)(ws + (128ull << 20)); //  8MB
    unsigned short* vtb  = (unsigned short*)(ws + (136ull << 20)); //  8MB  (end 144MB)
    unsigned short* ctxb = xb;   // xb dead after QKV GEMM
    unsigned short* woT  = wqT;  // wqT dead after QKV GEMM

    const int M = B_ * S_;  // 4096
    dim3 blk(256);

    // ---- pre-convert activations + weights to bf16 (weights transposed [N][K])
    convert_bf16<<<(int)(((size_t)M * DIM_ / 4 + 255) / 256), blk, 0, stream>>>(
        x, xb, (long long)M * DIM_);
    transpose_conv<<<dim3(DIM_ / 32, DIM_ / 32), blk, 0, stream>>>(wq, wqT, DIM_, DIM_);
    transpose_conv<<<dim3((NKV_ * HD_) / 32, DIM_ / 32), blk, 0, stream>>>(wk, wkT, DIM_, NKV_ * HD_);
    transpose_conv<<<dim3((NKV_ * HD_) / 32, DIM_ / 32), blk, 0, stream>>>(wv, wvT, DIM_, NKV_ * HD_);

    // ---- fused Q|K|V projection (N=6144, 1536 blocks = 6 blocks/CU)
    gemm_qkv<<<dim3(M / 128, (NH_ * HD_ + 2 * NKV_ * HD_) / 128), blk, 0, stream>>>(
        xb, wqT, xqb, xk, new_v, M, DIM_);

    // wo transpose after QKV GEMM (reuses wqT region; stream-ordered)
    transpose_conv<<<dim3(DIM_ / 32, DIM_ / 32), blk, 0, stream>>>(wo, woT, DIM_, DIM_);

    // ---- RoPE + layout conversion
    const long long totalPairs = (long long)B_ * S_ * (HD_ / 2) * (NH_ + 2 * NKV_);
    rope2<<<(int)((totalPairs + 255) / 256), blk, 0, stream>>>(
        xqb, xk, new_v, fc, kbuf, vtb, new_k);

    // ---- attention
    flash_attn<<<B_ * NH_ * (S_ / 64), blk, 0, stream>>>(xqb, kbuf, vtb, ctxb);

    // ---- output projection
    gemm_bt<false><<<dim3(M / 128, DIM_ / 128), blk, 0, stream>>>(ctxb, woT, out, M, DIM_, DIM_);
}